// Round 4
// baseline (151.549 us; speedup 1.0000x reference)
//
#include <hip/hip_runtime.h>

#define D 4096

typedef float fx4 __attribute__((ext_vector_type(4)));

// ws layout (in floats):
//   P0 = 0        : colsum0 partials [64][4096]   (stripe-major, plain stores)
//   P1 = 262144   : colsum1 partials [64][4096]
//   RS1 = 524288  : rowsum1 [4096]
//   RS2 = 528384  : rowsum2 [4096]
//   MSG = 532480  : m0,m1,m2,m3 [4][4096]
#define P0  0
#define P1  262144
#define RS1 524288
#define RS2 528384
#define MSG 532480

// ---------------- pass 1: all reductions, one launch, 192 MB read ----------------
// 1344 blocks x 256 threads:
//   [0,256)    colsum t0: stripe (b>>2) of 64 rows, col-quarter (b&3); partial -> P0
//   [256,320)  fused t1: 64 rows/block; rowsum1 direct + colsum1 partial -> P1
//   [320,1344) rowsum t2: 4 rows/block, wave per row
__global__ void __launch_bounds__(256) reduce_all_kernel(
        const float* __restrict__ t0, const float* __restrict__ t1,
        const float* __restrict__ t2, float* __restrict__ ws) {
    int b = blockIdx.x;
    if (b < 256) {
        // ---- colsum of t0 ----
        int q = b & 3, s = b >> 2;
        int c4 = q * 256 + threadIdx.x;            // fx4-column 0..1023
        int r0 = s * 64;
        const fx4* A4 = (const fx4*)t0;
        fx4 acc = (fx4){0.f, 0.f, 0.f, 0.f};
        #pragma unroll 8
        for (int r = 0; r < 64; ++r)
            acc += A4[(size_t)(r0 + r) * (D / 4) + c4];
        ((fx4*)(ws + P0))[(size_t)s * (D / 4) + c4] = acc;
    } else if (b < 320) {
        // ---- fused t1: rowsum + colsum from one read ----
        int s = b - 256;                            // stripe 0..63
        int r0 = s * 64;
        int wid = threadIdx.x >> 6, lane = threadIdx.x & 63;
        const fx4* A4 = (const fx4*)t1;
        fx4 acc[16];
        #pragma unroll
        for (int j = 0; j < 16; ++j) acc[j] = (fx4){0.f, 0.f, 0.f, 0.f};
        for (int it = 0; it < 16; ++it) {
            int row = r0 + it * 4 + wid;
            const fx4* R = A4 + (size_t)row * (D / 4);
            float rs = 0.f;
            #pragma unroll
            for (int j = 0; j < 16; ++j) {
                fx4 v = R[lane + 64 * j];
                acc[j] += v;
                rs += (v.x + v.y) + (v.z + v.w);
            }
            #pragma unroll
            for (int o = 32; o > 0; o >>= 1) rs += __shfl_down(rs, o);
            if (lane == 0) ws[RS1 + row] = rs;
        }
        // cross-wave combine in LDS (4 serialized rounds)
        __shared__ fx4 cs[D / 4];
        for (int ww = 0; ww < 4; ++ww) {
            if (wid == ww) {
                #pragma unroll
                for (int j = 0; j < 16; ++j) {
                    int c = lane + 64 * j;
                    if (ww == 0) cs[c] = acc[j]; else cs[c] += acc[j];
                }
            }
            __syncthreads();
        }
        fx4* part1 = (fx4*)(ws + P1);
        #pragma unroll
        for (int k = 0; k < 4; ++k) {
            int c4 = threadIdx.x + 256 * k;
            part1[(size_t)s * (D / 4) + c4] = cs[c4];
        }
    } else {
        // ---- rowsum of t2: wave per row ----
        int lb = b - 320;                           // 0..1023
        int wid = threadIdx.x >> 6, lane = threadIdx.x & 63;
        int row = lb * 4 + wid;
        const fx4* R = (const fx4*)(t2 + (size_t)row * D);
        float ssum = 0.f;
        #pragma unroll
        for (int j = 0; j < 16; ++j) {
            fx4 v = R[lane + 64 * j];
            ssum += (v.x + v.y) + (v.z + v.w);
        }
        #pragma unroll
        for (int o = 32; o > 0; o >>= 1) ssum += __shfl_down(ssum, o);
        if (lane == 0) ws[RS2 + row] = ssum;
    }
}

// ---------------- pass 2: message chain (single block of 1024) ----------------

__device__ __forceinline__ float block_sum_1024(float v, float* red) {
    #pragma unroll
    for (int o = 32; o > 0; o >>= 1) v += __shfl_down(v, o);
    int lane = threadIdx.x & 63, wid = threadIdx.x >> 6;
    if (lane == 0) red[wid] = v;
    __syncthreads();
    if (threadIdx.x == 0) {
        float t = 0.f;
        #pragma unroll
        for (int w = 0; w < 16; ++w) t += red[w];
        red[0] = t;
    }
    __syncthreads();
    float r = red[0];
    __syncthreads();
    return r;
}

__global__ void __launch_bounds__(1024) messages_kernel(
        const float* __restrict__ ws,
        const int* __restrict__ op0, const int* __restrict__ op1,
        const int* __restrict__ op2, const int* __restrict__ op3,
        float* __restrict__ ws_w) {
    __shared__ float cs0[D], cs1[D];
    __shared__ float m0[D], m1[D], m2[D], m3[D];
    __shared__ float red[16];
    int tid = threadIdx.x;

    // issue op-index loads first (independent of everything)
    int s0[4], d0[4], s1[4], d1[4], s2[4], d2[4], s3[4], d3[4];
    #pragma unroll
    for (int k = 0; k < 4; ++k) {
        int i = tid + k * 1024;
        s0[k] = op0[i]; d0[k] = op0[D + i];
        s1[k] = op1[i]; d1[k] = op1[D + i];
        s2[k] = op2[i]; d2[k] = op2[D + i];
        s3[k] = op3[i]; d3[k] = op3[D + i];
    }

    // reduce colsum partials -> LDS cs0, cs1 (overlaps with op-load latency)
    {
        const fx4* part0 = (const fx4*)(ws + P0);
        const fx4* part1 = (const fx4*)(ws + P1);
        fx4 a0 = (fx4){0.f, 0.f, 0.f, 0.f};
        fx4 a1 = (fx4){0.f, 0.f, 0.f, 0.f};
        #pragma unroll 8
        for (int s = 0; s < 64; ++s) {
            a0 += part0[(size_t)s * (D / 4) + tid];
            a1 += part1[(size_t)s * (D / 4) + tid];
        }
        ((fx4*)cs0)[tid] = a0;
        ((fx4*)cs1)[tid] = a1;
    }

    // rowsum gathers from global (prefetch; only depend on s2/s3)
    float g2[4], g3[4];
    #pragma unroll
    for (int k = 0; k < 4; ++k) {
        g2[k] = ws[RS2 + s2[k]];
        g3[k] = ws[RS1 + s3[k]];
    }

    #pragma unroll
    for (int k = 0; k < 4; ++k) {
        int i = tid + k * 1024;
        m0[i] = 0.f; m1[i] = 0.f; m2[i] = 0.f; m3[i] = 0.f;
    }
    __syncthreads();

    // m0 = remap(colsum0, op0)
    #pragma unroll
    for (int k = 0; k < 4; ++k) atomicAdd(&m0[d0[k]], cs0[s0[k]]);
    __syncthreads();

    // S0 = sum(m0)
    float p = 0.f;
    #pragma unroll
    for (int k = 0; k < 4; ++k) p += m0[tid + k * 1024];
    float S0 = block_sum_1024(p, red);

    // m1 = remap(colsum1 + S0, op1)
    #pragma unroll
    for (int k = 0; k < 4; ++k) atomicAdd(&m1[d1[k]], cs1[s1[k]] + S0);
    __syncthreads();

    // m2 = remap(rowsum2 + 4095*m1, op2)
    #pragma unroll
    for (int k = 0; k < 4; ++k)
        atomicAdd(&m2[d2[k]], g2[k] + 4095.0f * m1[s2[k]]);
    __syncthreads();

    // S2 = sum(m2)
    p = 0.f;
    #pragma unroll
    for (int k = 0; k < 4; ++k) p += m2[tid + k * 1024];
    float S2 = block_sum_1024(p, red);

    // m3 = remap(rowsum1 + 4095*m0 + S2, op3)
    #pragma unroll
    for (int k = 0; k < 4; ++k)
        atomicAdd(&m3[d3[k]], g3[k] + 4095.0f * m0[s3[k]] + S2);
    __syncthreads();

    // export
    #pragma unroll
    for (int k = 0; k < 4; ++k) {
        int i = tid + k * 1024;
        ws_w[MSG + 0 * D + i] = m0[i];
        ws_w[MSG + 1 * D + i] = m1[i];
        ws_w[MSG + 2 * D + i] = m2[i];
        ws_w[MSG + 3 * D + i] = m3[i];
    }
}

// ---------------- pass 3: apply broadcasts ----------------
// 3*D blocks x 256; block b: row (b & 4095) of matrix (b >> 12).
__global__ void __launch_bounds__(256) apply_kernel(
        const float* __restrict__ t0, const float* __restrict__ t1,
        const float* __restrict__ t2, const float* __restrict__ msgs,
        float* __restrict__ out) {
    int b = blockIdx.x;
    int mat = b >> 12;
    int row = b & (D - 1);
    const float* m0 = msgs + 0 * D;
    const float* m1 = msgs + 1 * D;
    const float* m2 = msgs + 2 * D;
    const float* m3 = msgs + 3 * D;
    size_t base = (size_t)row * D;
    fx4* dst = (fx4*)(out + (size_t)mat * D * D + base);

    if (mat == 0) {
        const fx4* src = (const fx4*)(t0 + base);
        const fx4* c4 = (const fx4*)m3;
        for (int i = threadIdx.x; i < D / 4; i += 256) {
            fx4 r = __builtin_nontemporal_load(&src[i]) + c4[i];
            __builtin_nontemporal_store(r, &dst[i]);
        }
    } else if (mat == 1) {
        const fx4* src = (const fx4*)(t1 + base);
        const fx4* c4 = (const fx4*)m2;
        float rr = m0[row];
        for (int i = threadIdx.x; i < D / 4; i += 256) {
            fx4 r = __builtin_nontemporal_load(&src[i]) + c4[i] + rr;
            __builtin_nontemporal_store(r, &dst[i]);
        }
    } else {
        const fx4* src = (const fx4*)(t2 + base);
        float rr = m1[row];
        for (int i = threadIdx.x; i < D / 4; i += 256) {
            fx4 r = __builtin_nontemporal_load(&src[i]) + rr;
            __builtin_nontemporal_store(r, &dst[i]);
        }
    }
}

extern "C" void kernel_launch(void* const* d_in, const int* in_sizes, int n_in,
                              void* d_out, int out_size, void* d_ws, size_t ws_size,
                              hipStream_t stream) {
    const float* t0 = (const float*)d_in[0];
    const float* t1 = (const float*)d_in[1];
    const float* t2 = (const float*)d_in[2];
    const int* op0 = (const int*)d_in[3];
    const int* op1 = (const int*)d_in[4];
    const int* op2 = (const int*)d_in[5];
    const int* op3 = (const int*)d_in[6];
    float* out = (float*)d_out;
    float* ws = (float*)d_ws;

    reduce_all_kernel<<<1344, 256, 0, stream>>>(t0, t1, t2, ws);
    messages_kernel<<<1, 1024, 0, stream>>>(ws, op0, op1, op2, op3, ws);
    apply_kernel<<<3 * D, 256, 0, stream>>>(t0, t1, t2, ws + MSG, out);
}